// Round 11
// baseline (191.871 us; speedup 1.0000x reference)
//
#include <hip/hip_runtime.h>

#define SEQ      512
#define BATCH    64
#define NTAG     64
#define STARTTAG 62
#define ENDTAG   63
#define TILE     4096
#define L2E      1.44269504088896340736f
#define LN2      0.69314718055994530942f
#define ESH      7.0f     // fold 2^-7 per-step rescale into exp

typedef float f32x4 __attribute__((ext_vector_type(4)));
typedef short s16x8 __attribute__((ext_vector_type(8)));
typedef int   i32x2 __attribute__((ext_vector_type(2)));
typedef int   i32x4 __attribute__((ext_vector_type(4)));

__device__ __forceinline__ unsigned lofs(const void* p) {
    return (unsigned)(size_t)(const __attribute__((address_space(3))) char*)p;
}
#define LDSW2(a, v)  asm volatile("ds_write_b64 %0, %1" :: "v"(a), "v"(v))
#define LDSW1(a, v)  asm volatile("ds_write_b32 %0, %1" :: "v"(a), "v"(v))
#define LDSR4I(r, a) asm volatile("ds_read_b128 %0, %1" : "=v"(r) : "v"(a))
// ONLY lgkmcnt(0) is used for waits: the loop contains compiler-tracked lgkm
// ops (shfl -> ds_bpermute), so a counted wait over a mixed queue is unsound
// (round-10 NaN). lgkmcnt(0) is safe and, with in-order DS completion, waits
// only marginally longer than a counted wait.
#define WAITL0() do { asm volatile("s_waitcnt lgkmcnt(0)" ::: "memory"); \
                      __builtin_amdgcn_sched_barrier(0); } while (0)

__device__ __forceinline__ unsigned cvtpk(float lo, float hi) {
    unsigned r;
    asm("v_cvt_pk_bf16_f32 %0, %1, %2" : "=v"(r) : "v"(lo), "v"(hi));
    return r;
}
__device__ __forceinline__ s16x8 cast8(i32x4 v) {
    union { i32x4 i; s16x8 h; } u; u.i = v; return u.h;
}

// R <- R * E_t serially over NST tiles; E_t = exp(s_t - 7ln2) in bf16.
// 4 waves; wave w owns R rows [16w,16w+16). 16B-granule XOR swizzle on both
// LDS tiles; frag reads are ds_read_b128. Pipelined step, one barrier + two
// lgkm(0) drains per step:
//   loads(k+2) | frag-reads(k) | E-VALU(k+1) | lgkm(0) | MFMA | E-writes(k+1)
//   | publish R | lgkm(0) | barrier.
template<int SPB>
__global__ __launch_bounds__(256, 4)
void crf_seg(const float* __restrict__ scores, float* __restrict__ ws)
{
    constexpr int NST = SEQ / SPB;
    __shared__ __align__(16) unsigned short ETs[2][NTAG * NTAG]; // 16 KB dbuf
    __shared__ __align__(16) unsigned short Rb[4][16 * NTAG];    // 8 KB, per-wave

    const int tid = (int)threadIdx.x;
    const int l = tid & 63, w = tid >> 6;
    const int b   = (int)blockIdx.x / SPB;
    const int sgi = (int)blockIdx.x % SPB;
    const int t0  = sgi * NST;
    const int g   = l >> 4;
    const int c   = l & 15;
    const int i0  = 4 * (tid >> 4);        // 16w + 4g
    const int j0  = 4 * (tid & 15);        // 4c

    const unsigned ET0 = lofs(ETs), ET1 = ET0 + 8192;
    const unsigned RbW = lofs(Rb) + (unsigned)(w * 2048);

    // identity init of private Rbuf (16B-granule swizzle)
    if (l < 32) {
        const int c0 = 2 * l;
        #pragma unroll
        for (int rr = 0; rr < 16; ++rr) {
            unsigned val = ((c0 == 16 * w + rr) ? 0x3F80u : 0u)
                         | (((c0 + 1 == 16 * w + rr) ? 0x3F80u : 0u) << 16);
            LDSW1(RbW + (unsigned)(rr * 128 + ((c0 * 2) ^ ((rr & 7) << 4))), val);
        }
    }
    WAITL0();

    // E-production split: CALC (VALU only -> wv regs) / WRITE (4 x ds_write_b64)
    #define EPCALC(TC, WV) do {                                               \
        _Pragma("unroll")                                                     \
        for (int jc = 0; jc < 4; ++jc) {                                      \
            const float e0 = __builtin_amdgcn_exp2f(fmaf((TC)[0][jc], L2E, -ESH)); \
            const float e1 = __builtin_amdgcn_exp2f(fmaf((TC)[1][jc], L2E, -ESH)); \
            const float e2 = __builtin_amdgcn_exp2f(fmaf((TC)[2][jc], L2E, -ESH)); \
            const float e3 = __builtin_amdgcn_exp2f(fmaf((TC)[3][jc], L2E, -ESH)); \
            (WV)[jc].x = (int)cvtpk(e0, e1); (WV)[jc].y = (int)cvtpk(e2, e3); \
        }                                                                     \
    } while (0)
    #define EPWRITE(WV, EPW) do {                                             \
        _Pragma("unroll")                                                     \
        for (int jc = 0; jc < 4; ++jc) {                                      \
            const int ja = j0 + jc;                                           \
            LDSW2((EPW) + (unsigned)(ja * 128 + ((i0 * 2) ^ ((ja & 7) << 4))), \
                  (WV)[jc]);                                                  \
        }                                                                     \
    } while (0)

    f32x4 Ta[4], Tb[4];
    {   // tile 0 -> Ta; E(0) -> ETs[0]; tile 1 -> Tb
        const float* gp = scores + ((size_t)(t0 * BATCH + b)) * TILE + (i0 * 64 + j0);
        #pragma unroll
        for (int ir = 0; ir < 4; ++ir) Ta[ir] = *(const f32x4*)(gp + ir * 64);
        i32x2 wv0[4];
        EPCALC(Ta, wv0);
        EPWRITE(wv0, ET0);
        const int t1 = (NST > 1) ? 1 : 0;
        const float* g1 = scores + ((size_t)((t0 + t1) * BATCH + b)) * TILE + (i0 * 64 + j0);
        #pragma unroll
        for (int ir = 0; ir < 4; ++ir) Tb[ir] = *(const f32x4*)(g1 + ir * 64);
        WAITL0();
        __builtin_amdgcn_s_barrier();
    }

    f32x4 acc[4];

    #define STEP(K, TC, TN) do {                                              \
        const int k_ = (K);                                                   \
        { /* issue loads for tile k+2 */                                      \
            int tt = k_ + 2; if (tt > NST - 1) tt = NST - 1;                  \
            const float* gp = scores + ((size_t)((t0 + tt) * BATCH + b)) * TILE \
                              + (i0 * 64 + j0);                               \
            _Pragma("unroll")                                                 \
            for (int ir = 0; ir < 4; ++ir) TN[ir] = *(const f32x4*)(gp + ir * 64); \
            __builtin_amdgcn_sched_barrier(0);                                \
        }                                                                     \
        /* frag reads (untracked): A from Rb, B from E[k&1] */                \
        const unsigned epR = (k_ & 1) ? ET1 : ET0;                            \
        i32x4 ai[2], bi[2][4];                                                \
        _Pragma("unroll")                                                     \
        for (int kt = 0; kt < 2; ++kt)                                        \
            LDSR4I(ai[kt], RbW + (unsigned)(c * 128 +                         \
                   ((64 * kt + 16 * g) ^ ((c & 7) << 4))));                   \
        _Pragma("unroll")                                                     \
        for (int kt = 0; kt < 2; ++kt)                                        \
            _Pragma("unroll")                                                 \
            for (int nt = 0; nt < 4; ++nt) {                                  \
                const int n = 16 * nt + c;                                    \
                LDSR4I(bi[kt][nt], epR + (unsigned)(n * 128 +                 \
                       ((64 * kt + 16 * g) ^ ((n & 7) << 4))));               \
            }                                                                 \
        /* E(k+1) VALU overlaps the ds_read latency; writes deferred */       \
        i32x2 wv[4];                                                          \
        EPCALC(TC, wv);                                                       \
        WAITL0();   /* all frag reads (and any tracked lgkm) retired */       \
        _Pragma("unroll")                                                     \
        for (int nt = 0; nt < 4; ++nt) acc[nt] = (f32x4){0.f, 0.f, 0.f, 0.f}; \
        _Pragma("unroll")                                                     \
        for (int kt = 0; kt < 2; ++kt) {                                      \
            const s16x8 af = cast8(ai[kt]);                                   \
            _Pragma("unroll")                                                 \
            for (int nt = 0; nt < 4; ++nt)                                    \
                acc[nt] = __builtin_amdgcn_mfma_f32_16x16x32_bf16(            \
                    af, cast8(bi[kt][nt]), acc[nt], 0, 0, 0);                 \
        }                                                                     \
        /* E(k+1) writes to the buffer read at k+1 (parity (k+1)&1) */        \
        const unsigned epW = ((k_ + 1) & 1) ? ET1 : ET0;                      \
        EPWRITE(wv, epW);                                                     \
        /* publish R (bf16, pair-packed via lane-xor) */                      \
        _Pragma("unroll")                                                     \
        for (int nt = 0; nt < 4; ++nt)                                        \
            _Pragma("unroll")                                                 \
            for (int r = 0; r < 4; ++r) {                                     \
                const float v = acc[nt][r];                                   \
                const float vp = __shfl_xor(v, 1);                            \
                const unsigned pw = (l & 1) ? cvtpk(vp, v) : cvtpk(v, vp);    \
                const int rl = 4 * g + r;                                     \
                if ((l & 1) == 0)                                             \
                    LDSW1(RbW + (unsigned)(rl * 128 +                         \
                          ((32 * nt + 2 * (l & 14)) ^ ((rl & 7) << 4))), pw); \
            }                                                                 \
        WAITL0();                                                             \
        __builtin_amdgcn_s_barrier();                                         \
    } while (0)

    for (int k = 0; k < NST; k += 2) {
        STEP(k,     Tb, Ta);
        STEP(k + 1, Ta, Tb);
    }
    #undef STEP
    #undef EPCALC
    #undef EPWRITE

    // epilogue: ln(acc) + NST*7*ln2 -> ws (fp32 log space)
    const float OFF = (float)NST * ESH * LN2;
    float* wp = ws + ((size_t)(b * SPB + sgi)) * 4096;
    #pragma unroll
    for (int nt = 0; nt < 4; ++nt)
        #pragma unroll
        for (int r = 0; r < 4; ++r) {
            const int row = 16 * w + 4 * g + r;
            const int col = 16 * nt + c;
            wp[row * 64 + col] = fmaf(__builtin_amdgcn_logf(acc[nt][r]), LN2, OFF);
        }
}

// Combine: chain log-vec through SPB log-matvecs; numerator gather.
template<int SPB>
__global__ __launch_bounds__(64, 1)
void crf_comb(const float* __restrict__ scores, const int* __restrict__ target,
              const int* __restrict__ mask, const float* __restrict__ ws,
              float* __restrict__ out)
{
    __shared__ float Ls[64][65];
    __shared__ float av[64];
    const int b = (int)blockIdx.x, l = (int)threadIdx.x;

    float a = (l == STARTTAG) ? 0.f : -1e30f;
    for (int g = 0; g < SPB; ++g) {
        const float* Lp = ws + ((size_t)(b * SPB + g)) * 4096 + l * 64;
        #pragma unroll
        for (int c4 = 0; c4 < 16; ++c4)
            *(f32x4*)&Ls[l][4 * c4] = *(const f32x4*)(Lp + 4 * c4);
        av[l] = a;
        __syncthreads();
        float M = -3.0e38f;
        #pragma unroll 8
        for (int m = 0; m < 64; ++m) M = fmaxf(M, av[m] + Ls[m][l]);
        float p = 0.f;
        #pragma unroll 8
        for (int m = 0; m < 64; ++m)
            p += __builtin_amdgcn_exp2f((av[m] + Ls[m][l] - M) * L2E);
        a = fmaf(__builtin_amdgcn_logf(p), LN2, M);
        __syncthreads();
    }
    const float den = __shfl(a, ENDTAG, 64);

    float num = 0.f;
    #pragma unroll
    for (int r = 0; r < 8; ++r) {
        const size_t tb = (size_t)(r * 64 + l) * BATCH + b;
        num += (float)mask[tb] * scores[tb * (size_t)TILE + target[tb]];
    }
    #pragma unroll
    for (int d = 1; d < 64; d <<= 1) num += __shfl_xor(num, d, 64);

    if (l == 0) out[b] = (den - num) * (1.0f / BATCH);
}

extern "C" void kernel_launch(void* const* d_in, const int* in_sizes, int n_in,
                              void* d_out, int out_size, void* d_ws, size_t ws_size,
                              hipStream_t stream) {
    const float* scores = (const float*)d_in[0];
    const int*   target = (const int*)d_in[1];
    const int*   mask   = (const int*)d_in[2];
    float*       out    = (float*)d_out;
    float*       ws     = (float*)d_ws;
    (void)in_sizes; (void)n_in; (void)out_size;

    const size_t need16 = (size_t)BATCH * 16 * 4096 * 4;
    const size_t need8  = (size_t)BATCH * 8  * 4096 * 4;
    if (ws_size >= need16) {
        hipLaunchKernelGGL(crf_seg<16>,  dim3(BATCH * 16), dim3(256), 0, stream, scores, ws);
        hipLaunchKernelGGL(crf_comb<16>, dim3(BATCH),      dim3(64),  0, stream,
                           scores, target, mask, ws, out);
    } else if (ws_size >= need8) {
        hipLaunchKernelGGL(crf_seg<8>,  dim3(BATCH * 8), dim3(256), 0, stream, scores, ws);
        hipLaunchKernelGGL(crf_comb<8>, dim3(BATCH),     dim3(64),  0, stream,
                           scores, target, mask, ws, out);
    } else {
        hipLaunchKernelGGL(crf_seg<4>,  dim3(BATCH * 4), dim3(256), 0, stream, scores, ws);
        hipLaunchKernelGGL(crf_comb<4>, dim3(BATCH),     dim3(64),  0, stream,
                           scores, target, mask, ws, out);
    }
}

// Round 13
// 181.034 us; speedup vs baseline: 1.0599x; 1.0599x over previous
//
#include <hip/hip_runtime.h>

#define SEQ      512
#define BATCH    64
#define NTAG     64
#define STARTTAG 62
#define ENDTAG   63
#define TILE     4096
#define L2E      1.44269504088896340736f
#define LN2      0.69314718055994530942f
#define ESH      7.0f     // fold 2^-7 per-step rescale into exp

typedef float f32x4 __attribute__((ext_vector_type(4)));
typedef short s16x8 __attribute__((ext_vector_type(8)));
typedef int   i32x2 __attribute__((ext_vector_type(2)));
typedef int   i32x4 __attribute__((ext_vector_type(4)));

__device__ __forceinline__ unsigned lofs(const void* p) {
    return (unsigned)(size_t)(const __attribute__((address_space(3))) char*)p;
}
#define LDSW2(a, v)  asm volatile("ds_write_b64 %0, %1" :: "v"(a), "v"(v))
#define LDSW1(a, v)  asm volatile("ds_write_b32 %0, %1" :: "v"(a), "v"(v))
#define LDSR4I(r, a) asm volatile("ds_read_b128 %0, %1" : "=v"(r) : "v"(a))
// lgkm queue is mixed (tracked shfl->bpermute) -> only lgkmcnt(0) (round-10).
// vmem is ALL tracked this round -> compiler emits sound counted vmcnt waits.
#define WAITL0() do { asm volatile("s_waitcnt lgkmcnt(0)" ::: "memory"); \
                      __builtin_amdgcn_sched_barrier(0); } while (0)

__device__ __forceinline__ unsigned cvtpk(float lo, float hi) {
    unsigned r;
    asm("v_cvt_pk_bf16_f32 %0, %1, %2" : "=v"(r) : "v"(lo), "v"(hi));
    return r;
}
__device__ __forceinline__ s16x8 cast8(i32x4 v) {
    union { i32x4 i; s16x8 h; } u; u.i = v; return u.h;
}

// R <- R * E_t over NST tiles; E_t = exp(s_t - 7ln2) bf16.
// Round-11 step body (passed) + 4-deep tracked register prefetch:
// step K consumes tile K+1 (E-prod) and loads tile K+4 into the buffer
// freed at step K-1 -> ~3 steps (~2100 cyc) of HBM-latency coverage,
// vs round 9's 1-deep (~700 cyc) that stalled every step.
template<int SPB>
__global__ __launch_bounds__(256, 2)
void crf_seg(const float* __restrict__ scores, float* __restrict__ ws)
{
    constexpr int NST = SEQ / SPB;
    static_assert(NST % 4 == 0, "unroll-4");
    __shared__ __align__(16) unsigned short ETs[2][NTAG * NTAG]; // 16 KB dbuf
    __shared__ __align__(16) unsigned short Rb[4][16 * NTAG];    // 8 KB per-wave

    const int tid = (int)threadIdx.x;
    const int l = tid & 63, w = tid >> 6;
    const int b   = (int)blockIdx.x / SPB;
    const int sgi = (int)blockIdx.x % SPB;
    const int t0  = sgi * NST;
    const int g   = l >> 4;
    const int c   = l & 15;
    const int i0  = 4 * (tid >> 4);        // 16w + 4g
    const int j0  = 4 * (tid & 15);        // 4c

    const unsigned ET0 = lofs(ETs), ET1 = ET0 + 8192;
    const unsigned RbW = lofs(Rb) + (unsigned)(w * 2048);

    // identity init of private Rbuf (16B-granule swizzle) — round-11 verbatim
    if (l < 32) {
        const int c0 = 2 * l;
        #pragma unroll
        for (int rr = 0; rr < 16; ++rr) {
            unsigned val = ((c0 == 16 * w + rr) ? 0x3F80u : 0u)
                         | (((c0 + 1 == 16 * w + rr) ? 0x3F80u : 0u) << 16);
            LDSW1(RbW + (unsigned)(rr * 128 + ((c0 * 2) ^ ((rr & 7) << 4))), val);
        }
    }

    #define EPCALC(TC, WV) do {                                               \
        _Pragma("unroll")                                                     \
        for (int jc = 0; jc < 4; ++jc) {                                      \
            const float e0 = __builtin_amdgcn_exp2f(fmaf((TC)[0][jc], L2E, -ESH)); \
            const float e1 = __builtin_amdgcn_exp2f(fmaf((TC)[1][jc], L2E, -ESH)); \
            const float e2 = __builtin_amdgcn_exp2f(fmaf((TC)[2][jc], L2E, -ESH)); \
            const float e3 = __builtin_amdgcn_exp2f(fmaf((TC)[3][jc], L2E, -ESH)); \
            (WV)[jc].x = (int)cvtpk(e0, e1); (WV)[jc].y = (int)cvtpk(e2, e3); \
        }                                                                     \
    } while (0)
    #define EPWRITE(WV, EPW) do {                                             \
        _Pragma("unroll")                                                     \
        for (int jc = 0; jc < 4; ++jc) {                                      \
            const int ja = j0 + jc;                                           \
            LDSW2((EPW) + (unsigned)(ja * 128 + ((i0 * 2) ^ ((ja & 7) << 4))), \
                  (WV)[jc]);                                                  \
        }                                                                     \
    } while (0)

    const float* gbase = scores + ((size_t)(t0 * BATCH + b)) * TILE + (i0 * 64 + j0);
    const size_t TSTEP = (size_t)BATCH * TILE;

    #define GLD(DST, T) do {                                                  \
        const float* gp = gbase + (size_t)(T) * TSTEP;                        \
        _Pragma("unroll")                                                     \
        for (int ir = 0; ir < 4; ++ir) (DST)[ir] = *(const f32x4*)(gp + ir * 64); \
    } while (0)

    // prologue: tiles 0..3 -> B0..B3 (tracked, 16 loads in flight); E0 -> ET0
    f32x4 B0[4], B1[4], B2[4], B3[4];
    GLD(B0, 0); GLD(B1, 1); GLD(B2, 2); GLD(B3, 3);
    {
        i32x2 wv0[4];
        EPCALC(B0, wv0);                       // compiler waits B0's loads only
        EPWRITE(wv0, ET0);
        WAITL0();                              // init + E0 writes drained
        __builtin_amdgcn_s_barrier();
    }

    f32x4 acc[4];

    // STEP(K): MFMA R·E_K (parity K&1), produce E_{K+1} from TC=tile K+1,
    // load tile K+4 into TN (buffer freed at step K-1).
    #define STEP(K, TN, TC) do {                                              \
        const int k_ = (K);                                                   \
        { int tt = k_ + 4; if (tt > NST - 1) tt = NST - 1;                    \
          GLD(TN, tt);                                                        \
          __builtin_amdgcn_sched_barrier(0); }                                \
        const unsigned epR = (k_ & 1) ? ET1 : ET0;                            \
        i32x4 ai[2], bi[2][4];                                                \
        _Pragma("unroll")                                                     \
        for (int kt = 0; kt < 2; ++kt)                                        \
            LDSR4I(ai[kt], RbW + (unsigned)(c * 128 +                         \
                   ((64 * kt + 16 * g) ^ ((c & 7) << 4))));                   \
        _Pragma("unroll")                                                     \
        for (int kt = 0; kt < 2; ++kt)                                        \
            _Pragma("unroll")                                                 \
            for (int nt = 0; nt < 4; ++nt) {                                  \
                const int n = 16 * nt + c;                                    \
                LDSR4I(bi[kt][nt], epR + (unsigned)(n * 128 +                 \
                       ((64 * kt + 16 * g) ^ ((n & 7) << 4))));               \
            }                                                                 \
        i32x2 wv[4];                                                          \
        EPCALC(TC, wv);    /* VALU/trans overlaps the ds_read latency */      \
        WAITL0();          /* frag reads (and any tracked lgkm) retired */    \
        _Pragma("unroll")                                                     \
        for (int nt = 0; nt < 4; ++nt) acc[nt] = (f32x4){0.f, 0.f, 0.f, 0.f}; \
        _Pragma("unroll")                                                     \
        for (int kt = 0; kt < 2; ++kt) {                                      \
            const s16x8 af = cast8(ai[kt]);                                   \
            _Pragma("unroll")                                                 \
            for (int nt = 0; nt < 4; ++nt)                                    \
                acc[nt] = __builtin_amdgcn_mfma_f32_16x16x32_bf16(            \
                    af, cast8(bi[kt][nt]), acc[nt], 0, 0, 0);                 \
        }                                                                     \
        EPWRITE(wv, ((k_ + 1) & 1) ? ET1 : ET0);                              \
        _Pragma("unroll")                                                     \
        for (int nt = 0; nt < 4; ++nt)                                        \
            _Pragma("unroll")                                                 \
            for (int r = 0; r < 4; ++r) {                                     \
                const float v = acc[nt][r];                                   \
                const float vp = __shfl_xor(v, 1);                            \
                const unsigned pw = (l & 1) ? cvtpk(vp, v) : cvtpk(v, vp);    \
                const int rl = 4 * g + r;                                     \
                if ((l & 1) == 0)                                             \
                    LDSW1(RbW + (unsigned)(rl * 128 +                         \
                          ((32 * nt + 2 * (l & 14)) ^ ((rl & 7) << 4))), pw); \
            }                                                                 \
        WAITL0();                                                             \
        __builtin_amdgcn_s_barrier();                                         \
    } while (0)

    for (int k = 0; k < NST; k += 4) {
        STEP(k + 0, B0, B1);
        STEP(k + 1, B1, B2);
        STEP(k + 2, B2, B3);
        STEP(k + 3, B3, B0);
    }
    #undef STEP
    #undef GLD
    #undef EPCALC
    #undef EPWRITE

    // epilogue: ln(acc) + NST*7*ln2 -> ws (fp32 log space)
    const float OFF = (float)NST * ESH * LN2;
    float* wp = ws + ((size_t)(b * SPB + sgi)) * 4096;
    #pragma unroll
    for (int nt = 0; nt < 4; ++nt)
        #pragma unroll
        for (int r = 0; r < 4; ++r) {
            const int row = 16 * w + 4 * g + r;
            const int col = 16 * nt + c;
            wp[row * 64 + col] = fmaf(__builtin_amdgcn_logf(acc[nt][r]), LN2, OFF);
        }
}

// Combine: chain log-vec through SPB log-matvecs; numerator gather.
template<int SPB>
__global__ __launch_bounds__(64, 1)
void crf_comb(const float* __restrict__ scores, const int* __restrict__ target,
              const int* __restrict__ mask, const float* __restrict__ ws,
              float* __restrict__ out)
{
    __shared__ float Ls[64][65];
    __shared__ float av[64];
    const int b = (int)blockIdx.x, l = (int)threadIdx.x;

    float a = (l == STARTTAG) ? 0.f : -1e30f;
    for (int g = 0; g < SPB; ++g) {
        const float* Lp = ws + ((size_t)(b * SPB + g)) * 4096 + l * 64;
        #pragma unroll
        for (int c4 = 0; c4 < 16; ++c4)
            *(f32x4*)&Ls[l][4 * c4] = *(const f32x4*)(Lp + 4 * c4);
        av[l] = a;
        __syncthreads();
        float M = -3.0e38f;
        #pragma unroll 8
        for (int m = 0; m < 64; ++m) M = fmaxf(M, av[m] + Ls[m][l]);
        float p = 0.f;
        #pragma unroll 8
        for (int m = 0; m < 64; ++m)
            p += __builtin_amdgcn_exp2f((av[m] + Ls[m][l] - M) * L2E);
        a = fmaf(__builtin_amdgcn_logf(p), LN2, M);
        __syncthreads();
    }
    const float den = __shfl(a, ENDTAG, 64);

    float num = 0.f;
    #pragma unroll
    for (int r = 0; r < 8; ++r) {
        const size_t tb = (size_t)(r * 64 + l) * BATCH + b;
        num += (float)mask[tb] * scores[tb * (size_t)TILE + target[tb]];
    }
    #pragma unroll
    for (int d = 1; d < 64; d <<= 1) num += __shfl_xor(num, d, 64);

    if (l == 0) out[b] = (den - num) * (1.0f / BATCH);
}

extern "C" void kernel_launch(void* const* d_in, const int* in_sizes, int n_in,
                              void* d_out, int out_size, void* d_ws, size_t ws_size,
                              hipStream_t stream) {
    const float* scores = (const float*)d_in[0];
    const int*   target = (const int*)d_in[1];
    const int*   mask   = (const int*)d_in[2];
    float*       out    = (float*)d_out;
    float*       ws     = (float*)d_ws;
    (void)in_sizes; (void)n_in; (void)out_size;

    const size_t need8 = (size_t)BATCH * 8 * 4096 * 4;
    const size_t need4 = (size_t)BATCH * 4 * 4096 * 4;
    if (ws_size >= need8) {
        hipLaunchKernelGGL(crf_seg<8>,  dim3(BATCH * 8), dim3(256), 0, stream, scores, ws);
        hipLaunchKernelGGL(crf_comb<8>, dim3(BATCH),     dim3(64),  0, stream,
                           scores, target, mask, ws, out);
    } else if (ws_size >= need4) {
        hipLaunchKernelGGL(crf_seg<4>,  dim3(BATCH * 4), dim3(256), 0, stream, scores, ws);
        hipLaunchKernelGGL(crf_comb<4>, dim3(BATCH),     dim3(64),  0, stream,
                           scores, target, mask, ws, out);
    } else {
        hipLaunchKernelGGL(crf_seg<2>,  dim3(BATCH * 2), dim3(256), 0, stream, scores, ws);
        hipLaunchKernelGGL(crf_comb<2>, dim3(BATCH),     dim3(64),  0, stream,
                           scores, target, mask, ws, out);
    }
}

// Round 14
// 141.734 us; speedup vs baseline: 1.3537x; 1.2773x over previous
//
#include <hip/hip_runtime.h>

#define SEQ      512
#define BATCH    64
#define NTAG     64
#define STARTTAG 62
#define ENDTAG   63
#define TILE     4096
#define L2E      1.44269504088896340736f
#define LN2      0.69314718055994530942f
#define ESH      7.0f     // fold 2^-7 per-step rescale into exp

typedef float f32x4 __attribute__((ext_vector_type(4)));
typedef short s16x8 __attribute__((ext_vector_type(8)));
typedef int   i32x2 __attribute__((ext_vector_type(2)));
typedef int   i32x4 __attribute__((ext_vector_type(4)));

__device__ __forceinline__ unsigned lofs(const void* p) {
    return (unsigned)(size_t)(const __attribute__((address_space(3))) char*)p;
}
#define LDSW2(a, v)  asm volatile("ds_write_b64 %0, %1" :: "v"(a), "v"(v))
#define LDSR4I(r, a) asm volatile("ds_read_b128 %0, %1" : "=v"(r) : "v"(a))
#define WAITL0() do { asm volatile("s_waitcnt lgkmcnt(0)" ::: "memory"); \
                      __builtin_amdgcn_sched_barrier(0); } while (0)

__device__ __forceinline__ unsigned cvtpk(float lo, float hi) {
    unsigned r;
    asm("v_cvt_pk_bf16_f32 %0, %1, %2" : "=v"(r) : "v"(lo), "v"(hi));
    return r;
}
__device__ __forceinline__ s16x8 cast8(i32x4 v) {
    union { i32x4 i; s16x8 h; } u; u.i = v; return u.h;
}

// Transposed chain: T <- E_t^T * T over NST tiles (T = R^T, T_0 = I).
// Wave w owns T cols [16w,16w+16) held IN REGISTERS as the MFMA B-operand
// (2 k-tiles x s16x8). A = E^T comes from LDS (ETs stored [col][k] = E^T
// [m][k], same layout as validated rounds). MFMA C output (col=lane&15 =
// same wave cols) converts to next step's B via 8 cvtpk + 16 shfl + 8
// cndmask -- no LDS round-trip, no Rb. One barrier + two lgkm(0) per step.
// Swizzle f(x)=(x+(x>>3))&7 on ETs k-offsets: conflict-free for BOTH the
// step-4 write rows (ja=4c+jc) and step-1 read rows (16mt+c).
template<int SPB>
__global__ __launch_bounds__(256, 1)
void crf_seg(const float* __restrict__ scores, float* __restrict__ ws)
{
    constexpr int NST = SEQ / SPB;
    static_assert(NST % 4 == 0 && NST >= 8, "ring");
    __shared__ __align__(16) unsigned short ETs[2][NTAG * NTAG]; // 16 KB dbuf

    const int tid = (int)threadIdx.x;
    const int l = tid & 63, w = tid >> 6;
    const int b   = (int)blockIdx.x / SPB;
    const int sgi = (int)blockIdx.x % SPB;
    const int t0  = sgi * NST;
    const int q   = l >> 4;
    const int c   = l & 15;
    const int i0  = 16 * w + 4 * q;        // E-production patch rows
    const int j0  = 4 * c;                 // E-production patch cols

    const unsigned ET0 = lofs(ETs);

    // swizzle constants
    unsigned fA[4], rowA[4], fW[4];
    #pragma unroll
    for (int mt = 0; mt < 4; ++mt) {
        const int row = 16 * mt + c;
        fA[mt]   = (unsigned)(((row + (row >> 3)) & 7) << 4);
        rowA[mt] = (unsigned)(row * 128);
    }
    #pragma unroll
    for (int jc = 0; jc < 4; ++jc) {
        const int ja = j0 + jc;
        fW[jc] = (unsigned)(((ja + (ja >> 3)) & 7) << 4);
    }

    #define EPCALC(TC, WV) do {                                               \
        _Pragma("unroll")                                                     \
        for (int jc = 0; jc < 4; ++jc) {                                      \
            const float e0 = __builtin_amdgcn_exp2f(fmaf((TC)[0][jc], L2E, -ESH)); \
            const float e1 = __builtin_amdgcn_exp2f(fmaf((TC)[1][jc], L2E, -ESH)); \
            const float e2 = __builtin_amdgcn_exp2f(fmaf((TC)[2][jc], L2E, -ESH)); \
            const float e3 = __builtin_amdgcn_exp2f(fmaf((TC)[3][jc], L2E, -ESH)); \
            (WV)[jc].x = (int)cvtpk(e0, e1); (WV)[jc].y = (int)cvtpk(e2, e3); \
        }                                                                     \
    } while (0)
    #define EPWRITE(WV, EPOFF) do {                                           \
        _Pragma("unroll")                                                     \
        for (int jc = 0; jc < 4; ++jc) {                                      \
            const int ja = j0 + jc;                                           \
            LDSW2(ET0 + (EPOFF) + (unsigned)(ja * 128) +                      \
                  (((unsigned)(2 * i0)) ^ fW[jc]), (WV)[jc]);                 \
        }                                                                     \
    } while (0)

    const float* gbase = scores + ((size_t)(t0 * BATCH + b)) * TILE + (i0 * 64 + j0);
    const size_t TSTEP = (size_t)BATCH * TILE;
    #define GLD(DST, T) do {                                                  \
        const float* gp = gbase + (size_t)(T) * TSTEP;                        \
        _Pragma("unroll")                                                     \
        for (int ir = 0; ir < 4; ++ir) (DST)[ir] = *(const f32x4*)(gp + ir * 64); \
    } while (0)

    // B-state: identity (T_0 = I): element e of kt is 1 iff 32kt+8q+e == 16w+c
    i32x4 bfr[2];
    #pragma unroll
    for (int kt = 0; kt < 2; ++kt) {
        const int d = (16 * w + c) - (32 * kt + 8 * q);
        i32x4 v;
        #pragma unroll
        for (int h = 0; h < 4; ++h)
            v[h] = ((d == 2 * h) ? 0x3F80 : 0) | ((d == 2 * h + 1) ? 0x3F800000 : 0);
        bfr[kt] = v;
    }

    // prologue: tiles 0..3 -> ring; E0 -> ETs[0]
    f32x4 B0[4], B1[4], B2[4], B3[4];
    GLD(B0, 0); GLD(B1, 1); GLD(B2, 2); GLD(B3, 3);
    {
        i32x2 wv0[4];
        EPCALC(B0, wv0);
        EPWRITE(wv0, 0u);
        WAITL0();
        __builtin_amdgcn_s_barrier();
    }

    f32x4 acc[4];

    // STEP K (0..NST-2): refill ring slot TN with tile K+4; A-reads of E_K;
    // E-calc of tile K+1 (TC); MFMA; C->B exchange; E-write; barrier.
    #define STEP(K, TN, TC) do {                                              \
        const int k_ = (K);                                                   \
        { int tt = k_ + 4; if (tt > NST - 1) tt = NST - 1;                    \
          GLD(TN, tt);                                                        \
          __builtin_amdgcn_sched_barrier(0); }                                \
        const unsigned epR = (k_ & 1) ? 8192u : 0u;                           \
        i32x4 ai[2][4];                                                       \
        _Pragma("unroll")                                                     \
        for (int kt = 0; kt < 2; ++kt)                                        \
            _Pragma("unroll")                                                 \
            for (int mt = 0; mt < 4; ++mt)                                    \
                LDSR4I(ai[kt][mt], ET0 + epR + rowA[mt] +                     \
                       (((unsigned)(64 * kt + 16 * q)) ^ fA[mt]));            \
        i32x2 wv[4];                                                          \
        EPCALC(TC, wv);                                                       \
        WAITL0();                                                             \
        _Pragma("unroll")                                                     \
        for (int mt = 0; mt < 4; ++mt) acc[mt] = (f32x4){0.f, 0.f, 0.f, 0.f}; \
        _Pragma("unroll")                                                     \
        for (int kt = 0; kt < 2; ++kt) {                                      \
            const s16x8 bf = cast8(bfr[kt]);                                  \
            _Pragma("unroll")                                                 \
            for (int mt = 0; mt < 4; ++mt)                                    \
                acc[mt] = __builtin_amdgcn_mfma_f32_16x16x32_bf16(            \
                    cast8(ai[kt][mt]), bf, acc[mt], 0, 0, 0);                 \
        }                                                                     \
        /* pack C to bf16 pairs: pk[mt][hh] = rows {16mt+4q+2hh, +1} */       \
        unsigned pk[4][2];                                                    \
        _Pragma("unroll")                                                     \
        for (int mt = 0; mt < 4; ++mt) {                                      \
            pk[mt][0] = cvtpk(acc[mt].x, acc[mt].y);                          \
            pk[mt][1] = cvtpk(acc[mt].z, acc[mt].w);                          \
        }                                                                     \
        /* exchange: B'[kt2].word[hp] from lane ((2(q&1)+(hp>>1))<<4)|c,     */\
        /* var pk[2kt2+(q>>1)][hp&1] -- select by own q>>1                   */\
        _Pragma("unroll")                                                     \
        for (int kt2 = 0; kt2 < 2; ++kt2) {                                   \
            i32x4 nb;                                                         \
            _Pragma("unroll")                                                 \
            for (int hp = 0; hp < 4; ++hp) {                                  \
                const int src = ((2 * (q & 1) + (hp >> 1)) << 4) | c;         \
                const int r0 = __shfl((int)pk[2 * kt2][hp & 1], src, 64);     \
                const int r1 = __shfl((int)pk[2 * kt2 + 1][hp & 1], src, 64); \
                nb[hp] = (q >> 1) ? r1 : r0;                                  \
            }                                                                 \
            bfr[kt2] = nb;                                                    \
        }                                                                     \
        EPWRITE(wv, ((k_ + 1) & 1) ? 8192u : 0u);                             \
        WAITL0();                                                             \
        __builtin_amdgcn_s_barrier();                                         \
    } while (0)

    for (int k = 0; k < NST - 4; k += 4) {
        STEP(k + 0, B0, B1);
        STEP(k + 1, B1, B2);
        STEP(k + 2, B2, B3);
        STEP(k + 3, B3, B0);
    }
    STEP(NST - 4, B0, B1);
    STEP(NST - 3, B1, B2);
    STEP(NST - 2, B2, B3);
    #undef STEP

    // final step (NST-1): A-reads + MFMA only
    {
        const unsigned epR = ((NST - 1) & 1) ? 8192u : 0u;
        i32x4 ai[2][4];
        #pragma unroll
        for (int kt = 0; kt < 2; ++kt)
            #pragma unroll
            for (int mt = 0; mt < 4; ++mt)
                LDSR4I(ai[kt][mt], ET0 + epR + rowA[mt] +
                       (((unsigned)(64 * kt + 16 * q)) ^ fA[mt]));
        WAITL0();
        #pragma unroll
        for (int mt = 0; mt < 4; ++mt) acc[mt] = (f32x4){0.f, 0.f, 0.f, 0.f};
        #pragma unroll
        for (int kt = 0; kt < 2; ++kt) {
            const s16x8 bf = cast8(bfr[kt]);
            #pragma unroll
            for (int mt = 0; mt < 4; ++mt)
                acc[mt] = __builtin_amdgcn_mfma_f32_16x16x32_bf16(
                    cast8(ai[kt][mt]), bf, acc[mt], 0, 0, 0);
        }
    }
    #undef GLD
    #undef EPCALC
    #undef EPWRITE

    // epilogue: stored[i][j] = ln T[i][j] + NST*7*ln2  (T = R^T)
    const float OFF = (float)NST * ESH * LN2;
    float* wp = ws + ((size_t)(b * SPB + sgi)) * 4096;
    #pragma unroll
    for (int mt = 0; mt < 4; ++mt)
        #pragma unroll
        for (int r = 0; r < 4; ++r) {
            const int row = 16 * mt + 4 * q + r;     // T row (= R col)
            const int col = 16 * w + c;              // T col (= R row)
            wp[row * 64 + col] = fmaf(__builtin_amdgcn_logf(acc[mt][r]), LN2, OFF);
        }
}

// Combine: stored[j][m] = ln R[m][j]; a'[j] = lse_m(a[m] + stored[j][m])
// -> thread j reduces over its OWN row (conflict-free via 65-pad).
template<int SPB>
__global__ __launch_bounds__(64, 1)
void crf_comb(const float* __restrict__ scores, const int* __restrict__ target,
              const int* __restrict__ mask, const float* __restrict__ ws,
              float* __restrict__ out)
{
    __shared__ float Ls[64][65];
    __shared__ float av[64];
    const int b = (int)blockIdx.x, l = (int)threadIdx.x;

    float a = (l == STARTTAG) ? 0.f : -1e30f;
    for (int g = 0; g < SPB; ++g) {
        const float* Lp = ws + ((size_t)(b * SPB + g)) * 4096 + l * 64;
        #pragma unroll
        for (int c4 = 0; c4 < 16; ++c4)
            *(f32x4*)&Ls[l][4 * c4] = *(const f32x4*)(Lp + 4 * c4);
        av[l] = a;
        __syncthreads();
        float M = -3.0e38f;
        #pragma unroll 8
        for (int m = 0; m < 64; ++m) M = fmaxf(M, av[m] + Ls[l][m]);
        float p = 0.f;
        #pragma unroll 8
        for (int m = 0; m < 64; ++m)
            p += __builtin_amdgcn_exp2f((av[m] + Ls[l][m] - M) * L2E);
        a = fmaf(__builtin_amdgcn_logf(p), LN2, M);
        __syncthreads();
    }
    const float den = __shfl(a, ENDTAG, 64);

    float num = 0.f;
    #pragma unroll
    for (int r = 0; r < 8; ++r) {
        const size_t tb = (size_t)(r * 64 + l) * BATCH + b;
        num += (float)mask[tb] * scores[tb * (size_t)TILE + target[tb]];
    }
    #pragma unroll
    for (int d = 1; d < 64; d <<= 1) num += __shfl_xor(num, d, 64);

    if (l == 0) out[b] = (den - num) * (1.0f / BATCH);
}

extern "C" void kernel_launch(void* const* d_in, const int* in_sizes, int n_in,
                              void* d_out, int out_size, void* d_ws, size_t ws_size,
                              hipStream_t stream) {
    const float* scores = (const float*)d_in[0];
    const int*   target = (const int*)d_in[1];
    const int*   mask   = (const int*)d_in[2];
    float*       out    = (float*)d_out;
    float*       ws     = (float*)d_ws;
    (void)in_sizes; (void)n_in; (void)out_size;

    const size_t need8 = (size_t)BATCH * 8 * 4096 * 4;
    const size_t need4 = (size_t)BATCH * 4 * 4096 * 4;
    if (ws_size >= need8) {
        hipLaunchKernelGGL(crf_seg<8>,  dim3(BATCH * 8), dim3(256), 0, stream, scores, ws);
        hipLaunchKernelGGL(crf_comb<8>, dim3(BATCH),     dim3(64),  0, stream,
                           scores, target, mask, ws, out);
    } else if (ws_size >= need4) {
        hipLaunchKernelGGL(crf_seg<4>,  dim3(BATCH * 4), dim3(256), 0, stream, scores, ws);
        hipLaunchKernelGGL(crf_comb<4>, dim3(BATCH),     dim3(64),  0, stream,
                           scores, target, mask, ws, out);
    } else {
        hipLaunchKernelGGL(crf_seg<2>,  dim3(BATCH * 2), dim3(256), 0, stream, scores, ws);
        hipLaunchKernelGGL(crf_comb<2>, dim3(BATCH),     dim3(64),  0, stream,
                           scores, target, mask, ws, out);
    }
}